// Round 2
// baseline (1541.817 us; speedup 1.0000x reference)
//
#include <hip/hip_runtime.h>
#include <stdint.h>

#define DICT  24576
#define BLOCK 1024
#define NV    6                 // float4 loads per thread (6*1024*4 = 24576)
#define NB1   2048              // 11-bit pass 1
#define NB2   2048              // 11-bit pass 2
#define NB3   1024              // 10-bit pass 3
#define NCOPY 4                 // pass-1 histogram copies
#define HPAD  8                 // copy stride pad: copy c starts at bank offset c*8
#define HSTRIDE (NB1 + HPAD)
#define CAND_CAP 3072
#define EQCAP 1024

// order-preserving float -> uint32 key (ascending)
__device__ __forceinline__ uint32_t f2key(float f) {
    uint32_t u = __float_as_uint(f);
    return (u & 0x80000000u) ? ~u : (u | 0x80000000u);
}

// All-wave redundant scan over NB ascending-key buckets: find bucket holding
// the r-th largest. Results are wave-uniform (broadcast via ballot/shfl, no
// LDS round-trip, no extra barrier).
template<int NB>
__device__ __forceinline__ void scan_hist(const uint32_t* __restrict__ hist,
                                          uint32_t r, int lane,
                                          uint32_t& bstar, uint32_t& rin,
                                          uint32_t& hcnt) {
    constexpr int PER_SEG = NB / 64;
    // per-lane segment sum; rotate index so lanes spread across banks
    uint32_t segsum = 0;
    #pragma unroll
    for (int i = 0; i < PER_SEG; ++i) {
        int idx = lane * PER_SEG + ((i + lane) & (PER_SEG - 1));
        segsum += hist[idx];
    }
    // inclusive suffix sum across 64 lanes: S[l] = sum_{i>=l} seg[i]
    uint32_t S = segsum;
    #pragma unroll
    for (int off = 1; off < 64; off <<= 1) {
        uint32_t v = __shfl_down(S, off, 64);
        if (lane + off < 64) S += v;
    }
    uint32_t A = S - segsum;                     // strictly above this segment
    unsigned long long m = __ballot((A < r) && (S >= r));   // exactly one lane
    int seg = __ffsll(m) - 1;
    uint32_t aboveSeg = __shfl(A, seg, 64);
    // resolve within the crossing segment (PER_SEG buckets on lanes 0..PER_SEG-1)
    uint32_t h = (lane < PER_SEG) ? hist[seg * PER_SEG + lane] : 0u;
    uint32_t S2 = h;
    #pragma unroll
    for (int off = 1; off < PER_SEG; off <<= 1) {
        uint32_t v = __shfl_down(S2, off, 64);
        if (lane + off < PER_SEG) S2 += v;
    }
    uint32_t A2 = aboveSeg + S2 - h;             // strictly above bucket
    unsigned long long m2 = __ballot((lane < PER_SEG) && (A2 < r) && (A2 + h >= r));
    int j = __ffsll(m2) - 1;
    bstar = (uint32_t)(seg * PER_SEG + j);
    rin   = r - __shfl(A2, j, 64);               // 1-based rank inside bucket
    hcnt  = __shfl(h, j, 64);                    // bucket population
}

__global__ __launch_bounds__(BLOCK, 8)  // 8 waves/EU = 32 waves/CU = 2 blocks/CU; caps VGPR at 64
void topk_kernel(const float* __restrict__ z,
                 const int* __restrict__ kp,
                 float* __restrict__ out) {
    __shared__ uint32_t hist[NCOPY * HSTRIDE];   // ~32.9 KB, reused across passes
    __shared__ uint32_t candKey[CAND_CAP];       // 12 KB
    __shared__ uint32_t candIdx[CAND_CAP];       // 12 KB
    __shared__ uint32_t eqIdx[EQCAP];            // 4 KB
    __shared__ uint32_t candCount, eqCount;

    const int tid  = threadIdx.x;
    const int lane = tid & 63;
    const int row  = blockIdx.x;
    const uint32_t k = (uint32_t)kp[0];

    const float4* __restrict__ zr  = (const float4*)(z + (size_t)row * DICT);
    float4* __restrict__ outr = (float4*)(out + (size_t)row * DICT);

    // ---- Pass 1: stream row (HBM), 11-bit histogram, 4 bank-staggered copies
    for (int i = tid; i < NCOPY * HSTRIDE; i += BLOCK) hist[i] = 0;
    __syncthreads();
    uint32_t* myh = hist + ((tid >> 6) & (NCOPY - 1)) * HSTRIDE;
    #pragma unroll
    for (int half = 0; half < 2; ++half) {
        float4 v[3];
        #pragma unroll
        for (int j = 0; j < 3; ++j) v[j] = zr[(half * 3 + j) * BLOCK + tid];
        #pragma unroll
        for (int j = 0; j < 3; ++j) {
            atomicAdd(&myh[f2key(v[j].x) >> 21], 1u);
            atomicAdd(&myh[f2key(v[j].y) >> 21], 1u);
            atomicAdd(&myh[f2key(v[j].z) >> 21], 1u);
            atomicAdd(&myh[f2key(v[j].w) >> 21], 1u);
        }
    }
    __syncthreads();
    for (int i = tid; i < NB1; i += BLOCK)
        hist[i] = hist[i] + hist[HSTRIDE + i] + hist[2 * HSTRIDE + i] + hist[3 * HSTRIDE + i];
    __syncthreads();
    uint32_t b1, r1, h1;
    scan_hist<NB1>(hist, k, lane, b1, r1, h1);

    // ---- Pass 2: re-read row (L2-hot), compact T-bucket candidates, 11-bit hist
    __syncthreads();                             // all waves done reading hist
    for (int i = tid; i < NB2; i += BLOCK) hist[i] = 0;
    if (tid == 0) { candCount = 0; eqCount = 0; }
    __syncthreads();
    #pragma unroll
    for (int j = 0; j < NV; ++j) {
        float4 vv = zr[j * BLOCK + tid];
        uint32_t kk[4] = { f2key(vv.x), f2key(vv.y), f2key(vv.z), f2key(vv.w) };
        #pragma unroll
        for (int c = 0; c < 4; ++c) {
            if ((kk[c] >> 21) == b1) {
                atomicAdd(&hist[(kk[c] >> 10) & (NB2 - 1)], 1u);
                uint32_t slot = atomicAdd(&candCount, 1u);
                if (slot < CAND_CAP) {
                    candKey[slot] = kk[c];
                    candIdx[slot] = (uint32_t)(j * (BLOCK * 4) + tid * 4 + c);
                }
            }
        }
    }
    __syncthreads();
    uint32_t b2, r2, h2;
    scan_hist<NB2>(hist, r1, lane, b2, r2, h2);
    const uint32_t pre22 = (b1 << 11) | b2;
    const uint32_t nc = candCount;               // block-uniform after barrier

    // ---- Pass 3: 10-bit hist from candidate list (global fallback on overflow)
    __syncthreads();
    for (int i = tid; i < NB3; i += BLOCK) hist[i] = 0;
    __syncthreads();
    if (nc <= CAND_CAP) {
        for (uint32_t i = tid; i < nc; i += BLOCK) {
            uint32_t kk = candKey[i];
            if ((kk >> 10) == pre22) atomicAdd(&hist[kk & (NB3 - 1)], 1u);
        }
    } else {
        #pragma unroll
        for (int j = 0; j < NV; ++j) {
            float4 vv = zr[j * BLOCK + tid];
            uint32_t kk[4] = { f2key(vv.x), f2key(vv.y), f2key(vv.z), f2key(vv.w) };
            #pragma unroll
            for (int c = 0; c < 4; ++c)
                if ((kk[c] >> 10) == pre22) atomicAdd(&hist[kk[c] & (NB3 - 1)], 1u);
        }
    }
    __syncthreads();
    uint32_t b3, r3, h3;
    scan_hist<NB3>(hist, r2, lane, b3, r3, h3);
    const uint32_t T = (pre22 << 10) | b3;       // exact key of k-th largest
    // r3 = how many key==T to keep (stable: lowest indices). h3 = |key==T|.

    // ---- Tie list: only needed if duplicates of T straddle the k boundary
    const bool needTies = (r3 < h3);             // block-uniform
    if (needTies) {
        if (nc <= CAND_CAP) {
            for (uint32_t i = tid; i < nc; i += BLOCK)
                if (candKey[i] == T) {
                    uint32_t s = atomicAdd(&eqCount, 1u);
                    if (s < EQCAP) eqIdx[s] = candIdx[i];
                }
        } else {
            #pragma unroll
            for (int j = 0; j < NV; ++j) {
                float4 vv = zr[j * BLOCK + tid];
                uint32_t kk[4] = { f2key(vv.x), f2key(vv.y), f2key(vv.z), f2key(vv.w) };
                #pragma unroll
                for (int c = 0; c < 4; ++c)
                    if (kk[c] == T) {
                        uint32_t s = atomicAdd(&eqCount, 1u);
                        if (s < EQCAP) eqIdx[s] = (uint32_t)(j * (BLOCK * 4) + tid * 4 + c);
                    }
            }
        }
        __syncthreads();
    }
    const uint32_t ec = needTies ? (eqCount < EQCAP ? eqCount : EQCAP) : 0u;

    // ---- Output: re-read row (L2-hot), threshold-select, coalesced store
    #pragma unroll
    for (int j = 0; j < NV; ++j) {
        float4 vv = zr[j * BLOCK + tid];
        float vals[4] = { vv.x, vv.y, vv.z, vv.w };
        float o[4];
        #pragma unroll
        for (int c = 0; c < 4; ++c) {
            uint32_t kk = f2key(vals[c]);
            float val = 0.0f;
            if (kk > T) {
                val = vals[c];
            } else if (kk == T) {
                if (!needTies) {
                    val = vals[c];
                } else {
                    uint32_t gi = (uint32_t)(j * (BLOCK * 4) + tid * 4 + c);
                    uint32_t rank = 0;
                    for (uint32_t i = 0; i < ec; ++i) rank += (eqIdx[i] < gi) ? 1u : 0u;
                    if (rank < r3) val = vals[c];
                }
            }
            o[c] = val;
        }
        float4 ov; ov.x = o[0]; ov.y = o[1]; ov.z = o[2]; ov.w = o[3];
        outr[j * BLOCK + tid] = ov;
    }
}

extern "C" void kernel_launch(void* const* d_in, const int* in_sizes, int n_in,
                              void* d_out, int out_size, void* d_ws, size_t ws_size,
                              hipStream_t stream) {
    const float* z  = (const float*)d_in[0];
    const int*   kp = (const int*)d_in[1];
    float* out = (float*)d_out;
    const int batch = in_sizes[0] / DICT;
    topk_kernel<<<dim3(batch), dim3(BLOCK), 0, stream>>>(z, kp, out);
}